// Round 2
// baseline (263.216 us; speedup 1.0000x reference)
//
#include <hip/hip_runtime.h>
#include <hip/hip_cooperative_groups.h>

#define N_NODES 50000
#define N_EDGES 800000
#define D 128
#define NBUCK 196   // ceil(50000/256) buckets of 256 nodes (dst>>8)
#define CAP 4800    // per-bucket capacity; mean 4096, sigma ~64 -> 11 sigma
#define CHUNK 4096  // edges per passA block (16/thread)
#define PA_BLKS ((N_EDGES + CHUNK - 1) / CHUNK)  // 196
#define FB_BLKS 12500                            // N_NODES*64/256
#define WT_BLKS 64                               // 16384/256
#define APAD 132    // acc row pitch in f32: 16B-aligned (132*4=528=33*16) and
                    // 132%32=4 -> rows skew 4 banks -> GEMM A-reads <=2-way
#define LDS_BYTES (256 * APAD * 4)  // 135,168 B dynamic LDS

typedef __attribute__((ext_vector_type(8))) short short8;
typedef __attribute__((ext_vector_type(4))) float f32x4;

__device__ __forceinline__ unsigned short f2bf(float f) {
    unsigned u = __float_as_uint(f);
    u += 0x7fff + ((u >> 16) & 1);  // RNE
    return (unsigned short)(u >> 16);
}
__device__ __forceinline__ float lo16f(unsigned u) { return __uint_as_float(u << 16); }
__device__ __forceinline__ float hi16f(unsigned u) { return __uint_as_float(u & 0xffff0000u); }

// ---------------------------------------------------------------------------
// K1 (IDENTICAL to the proven R0 prep_passA): passA buckets edges by dst>>8
// into tmp with per-block LDS histograms + one global reservation per
// (block,bucket) -> contiguous runs of ~21 entries per bucket per block, so
// the 8B scatter writes merge into full lines (this is what R1's flat
// scatter lost: 52MB of random-line HBM writes). prep converts feature ->
// packed-bf16 fb and W -> bf16 n-major Wt. gcur pre-zeroed via memsetAsync;
// final gcur[b] == bucket edge count (consumed directly by agg_fused).
// ---------------------------------------------------------------------------
__global__ __launch_bounds__(256) void prep_passA(
    const float2* __restrict__ feat2, unsigned* __restrict__ fb,
    const float* __restrict__ W, unsigned short* __restrict__ Wt,
    const int* __restrict__ esrc, const int* __restrict__ edst,
    const float* __restrict__ ew, int* __restrict__ gcur,
    uint2* __restrict__ tmp) {
    __shared__ int lh[NBUCK], lbase[NBUCK], lcur[NBUCK];
    int blk = blockIdx.x, t = threadIdx.x;

    if (blk >= PA_BLKS) {
        int b2 = blk - PA_BLKS;
        if (b2 < FB_BLKS) {
            int i = b2 * 256 + t;
            float2 f = feat2[i];
            fb[i] = (unsigned)f2bf(f.x) | ((unsigned)f2bf(f.y) << 16);
        } else {
            int idx = (b2 - FB_BLKS) * 256 + t;  // 16384 weight elements
            int n = idx >> 7, k = idx & 127;
            Wt[idx] = f2bf(W[k * 128 + n]);
        }
        return;
    }

    // ---- passA ----
    for (int i = t; i < NBUCK; i += 256) lh[i] = 0;
    __syncthreads();
    int e0 = blk * CHUNK;
    unsigned key[16];
    float wv[16];
#pragma unroll
    for (int j = 0; j < 16; ++j) {
        int e = e0 + j * 256 + t;
        if (e < N_EDGES) {
            int src = esrc[e], dd = edst[e];
            key[j] = (unsigned)src | ((unsigned)(dd & 255) << 16) |
                     ((unsigned)(dd >> 8) << 24);
            wv[j] = ew[e];
            atomicAdd(&lh[dd >> 8], 1);
        } else key[j] = 0xff000000u;  // invalid bucket marker
    }
    __syncthreads();
    for (int i = t; i < NBUCK; i += 256) {
        lbase[i] = atomicAdd(&gcur[i], lh[i]);
        lcur[i] = 0;
    }
    __syncthreads();
#pragma unroll
    for (int j = 0; j < 16; ++j) {
        int b = key[j] >> 24;
        if (b < NBUCK) {
            int r = atomicAdd(&lcur[b], 1);
            tmp[(size_t)b * CAP + lbase[b] + r] =
                make_uint2(key[j] & 0x00ffffffu, __float_as_uint(wv[j]));
        }
    }
}

// ---------------------------------------------------------------------------
// K2 (fused aggregate + GEMM, replaces passB/scan/scatter/sw/offsets):
// one block per bucket, 1024 threads (16 waves), acc[256][APAD] f32 in LDS.
// Wave w owns dst rows [w*16, w*16+16). Each wave ballot-scans the bucket's
// edge segment 64 keys at a time (keys L1/L2-resident; 16x redundant read is
// ~100MB of L2 traffic, ~3us aggregate), extracts up to 4 owned edges per
// round via readlane (SGPR broadcast, no DS traffic), issues their 4 row
// gathers back-to-back for ILP, merges same-row duplicates in registers
// (wave-uniform branches), then does <=4 LDS float2 rmw's into distinct rows.
// Row partitioning by wave -> no cross-wave races; in-wave DS ordering
// handles serial rmw to the same row. Absent extraction slots become
// contribution-0 dummies pinned to the wave's own first row (never another
// wave's row -> no rmw clobber race).
// After grid.sync() (tmp aliases d_out -> all tmp reads must complete
// device-wide before any out store): blend 0.5*acc+0.5*self, then per-wave
// 16x128 @ 128x128 MFMA GEMM straight out of LDS.
// mfma_f32_16x16x32_bf16: A[m=lane&15][k=quad*8+j], B[k][n=lane&15],
// D row=quad*4+reg, col=lane&15 (verified in prior rounds).
// ---------------------------------------------------------------------------
__global__ __launch_bounds__(1024) void agg_fused(
    const int* __restrict__ gcur, const uint2* __restrict__ tmp,
    const unsigned* __restrict__ fb, const unsigned short* __restrict__ Wt,
    float* __restrict__ out) {
    extern __shared__ float acc[];  // [256][APAD]
    int t = threadIdx.x;
    int w = t >> 6;       // wave 0..15: owns rows [w*16, w*16+16)
    int lane = t & 63;
    int b = blockIdx.x;

    // zero accumulators
    for (int i = t; i < 256 * APAD; i += 1024) acc[i] = 0.f;
    __syncthreads();

    int cnt = gcur[b];
    const uint2* seg = tmp + (size_t)b * CAP;
    unsigned dummy_kx = ((unsigned)(w * 16)) << 16;  // row w*16, src 0, w=0

    for (int c = 0; c < cnt; c += 64) {
        int idx = c + lane;
        uint2 kv = seg[idx < cnt ? idx : cnt - 1];
        int dl = (kv.x >> 16);  // entry.x has only src|dl<<16 (24 bits)
        bool own = (idx < cnt) && ((dl >> 4) == w);
        unsigned long long m = __ballot(own);
        while (m) {
            unsigned kx[4], ky[4];
#pragma unroll
            for (int q = 0; q < 4; ++q) {
                if (m) {
                    int sq = __builtin_ctzll(m);
                    m &= m - 1;
                    kx[q] = (unsigned)__builtin_amdgcn_readlane((int)kv.x, sq);
                    ky[q] = (unsigned)__builtin_amdgcn_readlane((int)kv.y, sq);
                } else {
                    kx[q] = dummy_kx;
                    ky[q] = 0u;
                }
            }
            int r0 = kx[0] >> 16, r1 = kx[1] >> 16, r2 = kx[2] >> 16, r3 = kx[3] >> 16;
            // 4 gathers in flight (SGPR base + lane*4 each)
            unsigned u0 = fb[(size_t)(kx[0] & 0xffffu) * 64 + lane];
            unsigned u1 = fb[(size_t)(kx[1] & 0xffffu) * 64 + lane];
            unsigned u2 = fb[(size_t)(kx[2] & 0xffffu) * 64 + lane];
            unsigned u3 = fb[(size_t)(kx[3] & 0xffffu) * 64 + lane];
            float w0 = __uint_as_float(ky[0]), w1 = __uint_as_float(ky[1]);
            float w2 = __uint_as_float(ky[2]), w3 = __uint_as_float(ky[3]);
            float cx0 = w0 * lo16f(u0), cy0 = w0 * hi16f(u0);
            float cx1 = w1 * lo16f(u1), cy1 = w1 * hi16f(u1);
            float cx2 = w2 * lo16f(u2), cy2 = w2 * hi16f(u2);
            float cx3 = w3 * lo16f(u3), cy3 = w3 * hi16f(u3);
            // merge same-row contributions (wave-uniform scalar branches)
            bool v1 = true, v2 = true, v3 = true;
            if (r1 == r0) { cx0 += cx1; cy0 += cy1; v1 = false; }
            if (r2 == r0) { cx0 += cx2; cy0 += cy2; v2 = false; }
            else if (v1 && r2 == r1) { cx1 += cx2; cy1 += cy2; v2 = false; }
            if (r3 == r0) { cx0 += cx3; cy0 += cy3; v3 = false; }
            else if (v1 && r3 == r1) { cx1 += cx3; cy1 += cy3; v3 = false; }
            else if (v2 && r3 == r2) { cx2 += cx3; cy2 += cy3; v3 = false; }
            {
                float2* p = (float2*)(acc + r0 * APAD) + lane;
                float2 v = *p; v.x += cx0; v.y += cy0; *p = v;
            }
            if (v1) {
                float2* p = (float2*)(acc + r1 * APAD) + lane;
                float2 v = *p; v.x += cx1; v.y += cy1; *p = v;
            }
            if (v2) {
                float2* p = (float2*)(acc + r2 * APAD) + lane;
                float2 v = *p; v.x += cx2; v.y += cy2; *p = v;
            }
            if (v3) {
                float2* p = (float2*)(acc + r3 * APAD) + lane;
                float2 v = *p; v.x += cx3; v.y += cy3; *p = v;
            }
        }
    }
    __syncthreads();

    // blend: acc = 0.5*acc + 0.5*feature(self)
    for (int i = t; i < 256 * 64; i += 1024) {
        int r = i >> 6, c = i & 63;
        int node = b * 256 + r;
        unsigned uf = (node < N_NODES) ? fb[(size_t)node * 64 + c] : 0u;
        float2* p = (float2*)(acc + r * APAD) + c;
        float2 v = *p;
        v.x = 0.5f * (v.x + lo16f(uf));
        v.y = 0.5f * (v.y + hi16f(uf));
        *p = v;
    }
    __syncthreads();

    // all tmp reads device-wide must be done before we overwrite d_out (alias)
    cooperative_groups::this_grid().sync();

    // GEMM: wave w computes rows [w*16, w*16+16) x all 128 output cols
    int quad = lane >> 4;
    int col = lane & 15;
    const float* arow = acc + (w * 16 + col) * APAD;  // A m-index = lane&15
    short8 a[4];
#pragma unroll
    for (int kk = 0; kk < 4; ++kk) {
        int k0 = kk * 32 + quad * 8;
        f32x4 x0 = *reinterpret_cast<const f32x4*>(arow + k0);
        f32x4 x1 = *reinterpret_cast<const f32x4*>(arow + k0 + 4);
        short8 af;
        af[0] = (short)f2bf(x0[0]); af[1] = (short)f2bf(x0[1]);
        af[2] = (short)f2bf(x0[2]); af[3] = (short)f2bf(x0[3]);
        af[4] = (short)f2bf(x1[0]); af[5] = (short)f2bf(x1[1]);
        af[6] = (short)f2bf(x1[2]); af[7] = (short)f2bf(x1[3]);
        a[kk] = af;
    }
#pragma unroll 1
    for (int n0 = 0; n0 < 8; ++n0) {
        const short8* bp = reinterpret_cast<const short8*>(Wt) + ((n0 * 16 + col) * 16 + quad);
        f32x4 accv = {0.f, 0.f, 0.f, 0.f};
        accv = __builtin_amdgcn_mfma_f32_16x16x32_bf16(a[0], bp[0],  accv, 0, 0, 0);
        accv = __builtin_amdgcn_mfma_f32_16x16x32_bf16(a[1], bp[4],  accv, 0, 0, 0);
        accv = __builtin_amdgcn_mfma_f32_16x16x32_bf16(a[2], bp[8],  accv, 0, 0, 0);
        accv = __builtin_amdgcn_mfma_f32_16x16x32_bf16(a[3], bp[12], accv, 0, 0, 0);
#pragma unroll
        for (int rr = 0; rr < 4; ++rr) {
            int node = b * 256 + w * 16 + quad * 4 + rr;
            if (node < N_NODES)
                out[(size_t)node * D + n0 * 16 + col] = accv[rr];
        }
    }
}

// ---------------------------------------------------------------------------
extern "C" void kernel_launch(void* const* d_in, const int* in_sizes, int n_in,
                              void* d_out, int out_size, void* d_ws, size_t ws_size,
                              hipStream_t stream) {
    const float* feat = (const float*)d_in[0];
    const int*   esrc = (const int*)d_in[1];
    const int*   edst = (const int*)d_in[2];
    const float* ew   = (const float*)d_in[3];
    const float* W    = (const float*)d_in[4];
    float*       out  = (float*)d_out;

    char* ws = (char*)d_ws;
    unsigned*       fb   = (unsigned*)(ws + 6400000);          // 12,800,000 (R0 offset kept)
    unsigned short* Wt   = (unsigned short*)(ws + 19400064);   //     32,768
    int*            gcur = (int*)(ws + 19432832);              //        784
    // tmp (7.53 MB) aliases d_out, dead once agg_fused passes grid.sync().
    uint2* tmp = (uint2*)d_out;

    static int attr_set = 0;
    if (!attr_set) {
        hipFuncSetAttribute((const void*)agg_fused,
                            hipFuncAttributeMaxDynamicSharedMemorySize, LDS_BYTES);
        attr_set = 1;
    }

    hipMemsetAsync(gcur, 0, NBUCK * sizeof(int), stream);
    prep_passA<<<PA_BLKS + FB_BLKS + WT_BLKS, 256, 0, stream>>>(
        (const float2*)feat, fb, W, Wt, esrc, edst, ew, gcur, tmp);

    const int* gcur_c = gcur;
    const uint2* tmp_c = tmp;
    const unsigned* fb_c = fb;
    const unsigned short* Wt_c = Wt;
    void* kargs[] = {(void*)&gcur_c, (void*)&tmp_c, (void*)&fb_c, (void*)&Wt_c,
                     (void*)&out};
    hipLaunchCooperativeKernel((void*)agg_fused, dim3(NBUCK), dim3(1024), kargs,
                               LDS_BYTES, stream);
}

// Round 4
// 146.474 us; speedup vs baseline: 1.7970x; 1.7970x over previous
//
#include <hip/hip_runtime.h>

#define N_NODES 50000
#define N_EDGES 800000
#define D 128
#define NBUCK 196   // ceil(50000/256) buckets of 256 nodes (dst>>8)
#define CAP 4800    // per-bucket capacity; mean 4096, sigma ~64 -> 11 sigma
#define CHUNK 4096  // edges per passA block (4/thread at 1024 threads)
#define PA_BLKS ((N_EDGES + CHUNK - 1) / CHUNK)  // 196
#define FB_BLKS 3125                             // N_NODES*64/1024
#define WT_BLKS 16                               // 16384/1024

typedef __attribute__((ext_vector_type(8))) short short8;
typedef __attribute__((ext_vector_type(4))) float f32x4;

__device__ __forceinline__ unsigned short f2bf(float f) {
    unsigned u = __float_as_uint(f);
    u += 0x7fff + ((u >> 16) & 1);  // RNE
    return (unsigned short)(u >> 16);
}
__device__ __forceinline__ float lo16f(unsigned u) { return __uint_as_float(u << 16); }
__device__ __forceinline__ float hi16f(unsigned u) { return __uint_as_float(u & 0xffff0000u); }

// ---------------------------------------------------------------------------
// K1: R0's proven passA (per-block LDS histogram -> one global reservation per
// (block,bucket) -> contiguous ~21-entry runs, so the 8B writes merge into
// full lines), now at 1024 threads/block (4 edges/thread) for 4x the waves on
// the latency-bound scatter phase. fb/Wt conversion blocks repartitioned.
// gcur pre-zeroed via memsetAsync; final gcur[b] == bucket edge count.
// ---------------------------------------------------------------------------
__global__ __launch_bounds__(1024) void prep_passA(
    const float2* __restrict__ feat2, unsigned* __restrict__ fb,
    const float* __restrict__ W, unsigned short* __restrict__ Wt,
    const int* __restrict__ esrc, const int* __restrict__ edst,
    const float* __restrict__ ew, int* __restrict__ gcur,
    uint2* __restrict__ tmp) {
    __shared__ int lh[NBUCK], lbase[NBUCK], lcur[NBUCK];
    int blk = blockIdx.x, t = threadIdx.x;

    if (blk >= PA_BLKS) {
        int b2 = blk - PA_BLKS;
        if (b2 < FB_BLKS) {
            int i = b2 * 1024 + t;
            float2 f = feat2[i];
            fb[i] = (unsigned)f2bf(f.x) | ((unsigned)f2bf(f.y) << 16);
        } else {
            int idx = (b2 - FB_BLKS) * 1024 + t;  // 16384 weight elements
            int n = idx >> 7, k = idx & 127;
            Wt[idx] = f2bf(W[k * 128 + n]);
        }
        return;
    }

    // ---- passA ----
    for (int i = t; i < NBUCK; i += 1024) lh[i] = 0;
    __syncthreads();
    int e0 = blk * CHUNK;
    unsigned key[4];
    float wv[4];
#pragma unroll
    for (int j = 0; j < 4; ++j) {
        int e = e0 + j * 1024 + t;
        if (e < N_EDGES) {
            int src = esrc[e], dd = edst[e];
            key[j] = (unsigned)src | ((unsigned)(dd & 255) << 16) |
                     ((unsigned)(dd >> 8) << 24);
            wv[j] = ew[e];
            atomicAdd(&lh[dd >> 8], 1);
        } else key[j] = 0xff000000u;  // invalid bucket marker
    }
    __syncthreads();
    for (int i = t; i < NBUCK; i += 1024) {
        lbase[i] = atomicAdd(&gcur[i], lh[i]);
        lcur[i] = 0;
    }
    __syncthreads();
#pragma unroll
    for (int j = 0; j < 4; ++j) {
        int b = key[j] >> 24;
        if (b < NBUCK) {
            int r = atomicAdd(&lcur[b], 1);
            tmp[(size_t)b * CAP + lbase[b] + r] =
                make_uint2(key[j] & 0x00ffffffu, __float_as_uint(wv[j]));
        }
    }
}

// ---------------------------------------------------------------------------
// K2: per-bucket counting sort -> offsets[] + per-node-grouped sw, now at
// 1024 threads/block (histogram + scatter loops drop 16 -> 4 iters/thread).
// Bucket base = tree-reduce of gcur[0..b-1] (each block only needs ITS base,
// not a full scan). Per-node offsets within the bucket via 256-entry
// Hillis-Steele among t<256 (all-thread __syncthreads, guarded work).
// ---------------------------------------------------------------------------
__global__ __launch_bounds__(1024) void passB(const int* __restrict__ gcur,
                                              const uint2* __restrict__ tmp,
                                              int* __restrict__ offsets,
                                              uint2* __restrict__ sw) {
    __shared__ int hist[256], ps[256];
    int b = blockIdx.x, t = threadIdx.x;

    // base = sum of gcur[0..b-1] (b <= 195 < 256: one entry per low thread)
    if (t < 256) ps[t] = (t < b) ? gcur[t] : 0;
    __syncthreads();
    for (int off = 128; off > 0; off >>= 1) {
        if (t < off) ps[t] += ps[t + off];
        __syncthreads();
    }
    int base = ps[0];
    int cnt = gcur[b];
    if (t < 256) hist[t] = 0;
    __syncthreads();

    const uint2* seg = tmp + (size_t)b * CAP;
    for (int i = t; i < cnt; i += 1024) atomicAdd(&hist[seg[i].x >> 16], 1);
    __syncthreads();

    int h = 0;
    if (t < 256) { h = hist[t]; ps[t] = h; }
    __syncthreads();
    for (int off = 1; off < 256; off <<= 1) {
        int x = 0;
        if (t < 256 && t >= off) x = ps[t - off];
        __syncthreads();
        if (t < 256) ps[t] += x;
        __syncthreads();
    }
    int o = 0;
    if (t < 256) {
        o = base + ps[t] - h;  // exclusive within-bucket + bucket base
        int node = b * 256 + t;
        if (node < N_NODES) offsets[node] = o;
    }
    if (b == NBUCK - 1 && t == 0) offsets[N_NODES] = N_EDGES;
    __syncthreads();
    if (t < 256) hist[t] = o;  // reuse as cursor
    __syncthreads();
    for (int i = t; i < cnt; i += 1024) {
        uint2 u = seg[i];
        int pos = atomicAdd(&hist[u.x >> 16], 1);
        sw[pos] = make_uint2(u.x & 0xffffu, u.y);
    }
}

// ---------------------------------------------------------------------------
// K3 (BYTE-IDENTICAL to the proven 46us version): block = 16 nodes, wave
// aggregates 4. __launch_bounds__(256,2) lifts the VGPR cap so a full
// 16-edge batch (p[16] sw entries, u[16] gathered rows) PLUS the next
// batch's pn[16] stay live -> ~32 loads in flight per wave.
// Tail batch is clamp-padded with weights zeroed -> all loops fixed-trip.
// Then blended bf16 rows -> Arows -> 16x128 @ 128x128 MFMA.
// mfma_f32_16x16x32_bf16: A[m=lane&15][k=quad*8+j], B[k][n=lane&15],
// D row=quad*4+reg, col=lane&15 (verified in prior rounds).
// ---------------------------------------------------------------------------
__global__ __launch_bounds__(256, 2) void agg_gemm(const int* __restrict__ offsets,
                                                   const uint2* __restrict__ sw,
                                                   const unsigned* __restrict__ fb,
                                                   const unsigned short* __restrict__ Wt,
                                                   float* __restrict__ out) {
    __shared__ unsigned Arows[16][68];
    int wave = threadIdx.x >> 6;
    int lane = threadIdx.x & 63;
    int row0 = blockIdx.x * 16;

#pragma unroll 1
    for (int i = 0; i < 4; ++i) {
        int n = __builtin_amdgcn_readfirstlane(row0 + wave * 4 + i);
        int b = offsets[n], e2 = offsets[n + 1];
        unsigned us = fb[(size_t)n * 64 + lane];  // self row
        float ax = 0.f, ay = 0.f;
        int e = b;
        int nfull = (e2 - b) >> 4;

        uint2 p[16];
        {   // preload first batch (clamped; OOB-safe: sw is followed by fb in ws)
            int rem = e2 - e;
#pragma unroll
            for (int j = 0; j < 16; ++j) {
                int idx = (j < rem) ? j : (rem > 0 ? rem - 1 : 0);
                p[j] = sw[e + idx];
            }
        }
#pragma unroll 1
        for (int t = 0; t < nfull; ++t) {
            unsigned u[16];
#pragma unroll
            for (int j = 0; j < 16; ++j) u[j] = fb[(size_t)p[j].x * 64 + lane];
            // prefetch next batch while the 16 gathers are in flight
            int en = e + 16;
            int rem = e2 - en;
            uint2 pn[16];
#pragma unroll
            for (int j = 0; j < 16; ++j) {
                int idx = (j < rem) ? j : (rem > 0 ? rem - 1 : 0);
                pn[j] = sw[en + idx];
            }
#pragma unroll
            for (int j = 0; j < 16; ++j) {
                float w = __uint_as_float(p[j].y);
                ax += w * lo16f(u[j]);
                ay += w * hi16f(u[j]);
            }
#pragma unroll
            for (int j = 0; j < 16; ++j) p[j] = pn[j];
            e = en;
        }
        int rem = e2 - e;
        if (rem > 0) {  // tail: p already holds the clamp-padded batch
            unsigned u[16];
#pragma unroll
            for (int j = 0; j < 16; ++j) u[j] = fb[(size_t)p[j].x * 64 + lane];
#pragma unroll
            for (int j = 0; j < 16; ++j) {
                float w = (j < rem) ? __uint_as_float(p[j].y) : 0.f;
                ax += w * lo16f(u[j]);
                ay += w * hi16f(u[j]);
            }
        }
        float rx = 0.5f * (ax + lo16f(us));
        float ry = 0.5f * (ay + hi16f(us));
        Arows[wave * 4 + i][lane] = (unsigned)f2bf(rx) | ((unsigned)f2bf(ry) << 16);
    }
    __syncthreads();

    int quad = lane >> 4;
    int col  = lane & 15;
    short8 a[4];
#pragma unroll
    for (int kk = 0; kk < 4; ++kk)
        a[kk] = *reinterpret_cast<const short8*>(&Arows[col][kk * 16 + quad * 4]);

#pragma unroll
    for (int ii = 0; ii < 2; ++ii) {
        int n0 = wave * 2 + ii;
        const short8* bp = reinterpret_cast<const short8*>(Wt) + ((n0 * 16 + col) * 16 + quad);
        f32x4 acc = {0.f, 0.f, 0.f, 0.f};
        acc = __builtin_amdgcn_mfma_f32_16x16x32_bf16(a[0], bp[0],  acc, 0, 0, 0);
        acc = __builtin_amdgcn_mfma_f32_16x16x32_bf16(a[1], bp[4],  acc, 0, 0, 0);
        acc = __builtin_amdgcn_mfma_f32_16x16x32_bf16(a[2], bp[8],  acc, 0, 0, 0);
        acc = __builtin_amdgcn_mfma_f32_16x16x32_bf16(a[3], bp[12], acc, 0, 0, 0);
#pragma unroll
        for (int rr = 0; rr < 4; ++rr)
            out[(size_t)(row0 + quad * 4 + rr) * D + n0 * 16 + col] = acc[rr];
    }
}

// ---------------------------------------------------------------------------
extern "C" void kernel_launch(void* const* d_in, const int* in_sizes, int n_in,
                              void* d_out, int out_size, void* d_ws, size_t ws_size,
                              hipStream_t stream) {
    const float* feat = (const float*)d_in[0];
    const int*   esrc = (const int*)d_in[1];
    const int*   edst = (const int*)d_in[2];
    const float* ew   = (const float*)d_in[3];
    const float* W    = (const float*)d_in[4];
    float*       out  = (float*)d_out;

    char* ws = (char*)d_ws;
    uint2*          sw      = (uint2*)(ws + 0);                   //  6,400,000
    unsigned*       fb      = (unsigned*)(ws + 6400000);          // 12,800,000
    int*            offsets = (int*)(ws + 19200000);              //    200,004
    unsigned short* Wt      = (unsigned short*)(ws + 19400064);   //     32,768
    int*            gcur    = (int*)(ws + 19432832);              //        784
    // tmp (7.53 MB) aliases d_out, dead until agg_gemm overwrites it.
    uint2* tmp = (uint2*)d_out;

    hipMemsetAsync(gcur, 0, NBUCK * sizeof(int), stream);
    prep_passA<<<PA_BLKS + FB_BLKS + WT_BLKS, 1024, 0, stream>>>(
        (const float2*)feat, fb, W, Wt, esrc, edst, ew, gcur, tmp);
    passB<<<NBUCK, 1024, 0, stream>>>(gcur, tmp, offsets, sw);
    agg_gemm<<<N_NODES / 16, 256, 0, stream>>>(offsets, sw, fb, Wt, out);
}